// Round 10
// baseline (189.893 us; speedup 1.0000x reference)
//
#include <hip/hip_runtime.h>
#include <stdint.h>

// Input  x[b,t,h,w,c] : (4, 200, 64, 64, 8) fp32   (105 MB)
// Output out[b,t,w,c,h]: (4, 200, 64, 8, 64) fp32  (105 MB)
// Per neuron, per 100-step chunk: acc += x[t]; if (acc > 2) { spike=1; acc=0; }
//
// Single fused kernel with FINE-GRAINED READ/WRITE INTERLEAVE.
// Evidence: all read-only phases cap at ~2.6-2.9 TB/s; all write-only phases
// run ~6.8-7.5 TB/s; the float4-copy ubench does 3.15 read + 3.15 write
// CONCURRENTLY (6.29 aggregate). Serializing the two phases (all prior
// rounds) wastes that concurrency. Here every loop iteration issues 16 B of
// load AND 16 B of store, so the chip sees a steady 50/50 demand mix.
//
// Geometry: 256 blocks x 256 threads. Block = (slab = b*2+chunk, wc-tile of
// 16) covering all 64 h -> 1024 neurons, 4/thread (h = 4*hloc + k).
// t processed in groups of 32 (bit-words): scan group g (4 dword loads /
// thread / plane) while storing group g-1 (1 float4 / thread / plane; per
// plane the block writes 4 KB CONTIGUOUS - K2's proven write shape).
// Bits cross groups via 4.4 KB LDS + per-group register hoist.
#define HWC   32768
#define TTOT  200
#define CHUNK 100

__global__ __launch_bounds__(256) void spike_pipe(const float* __restrict__ x,
                                                  float* __restrict__ out) {
    __shared__ uint32_t bits[64 * 17];        // [h 0..63][wcl 0..15 pad 17]

    unsigned bid  = blockIdx.x;               // [0,256)
    unsigned slab = bid & 7u;                 // XCD-aligned (round-9, neutral)
    unsigned wcT  = bid >> 3;                 // [0,32)
    unsigned wc0  = wcT * 16u;
    unsigned b    = slab >> 1, ch = slab & 1u;
    unsigned tid  = threadIdx.x;

    // ---- scan-role mapping: thread -> (wcl, h = 4*hloc + k) ----
    unsigned wcl  = tid & 15u;
    unsigned hloc = tid >> 4;                 // [0,16)
    const float* xb = x + (size_t)(b * TTOT + ch * CHUNK) * HWC
                    + (size_t)(hloc * 4u) * 512u + wc0 + wcl;

    // ---- store-role mapping: thread -> (wcs, h0s..h0s+3) ----
    unsigned wcs  = tid >> 4;                 // [0,16)
    unsigned h0s  = (tid & 15u) * 4u;         // 0,4,...,60
    unsigned rbase = b * TTOT + ch * CHUNK;
    float4*  o4   = (float4*)out;
    size_t   cidx = (((size_t)(wc0 + wcs) * 64u) + h0s) >> 2;  // float4 units

    float    a0 = 0.f, a1 = 0.f, a2 = 0.f, a3 = 0.f;  // accs persist across groups
    uint32_t w0 = 0u, w1 = 0u, w2 = 0u, w3 = 0u;      // current group's words
    uint32_t r0 = 0u, r1 = 0u, r2 = 0u, r3 = 0u;      // hoisted previous group

#define SCAN(T, J)                                                          \
    do {                                                                    \
        float v0 = xb[(size_t)(T) * HWC];                                   \
        float v1 = xb[(size_t)(T) * HWC + 512u];                            \
        float v2 = xb[(size_t)(T) * HWC + 1024u];                           \
        float v3 = xb[(size_t)(T) * HWC + 1536u];                           \
        a0 += v0; if (a0 > 2.0f) { w0 |= 1u << (J); a0 = 0.0f; }            \
        a1 += v1; if (a1 > 2.0f) { w1 |= 1u << (J); a1 = 0.0f; }            \
        a2 += v2; if (a2 > 2.0f) { w2 |= 1u << (J); a2 = 0.0f; }            \
        a3 += v3; if (a3 > 2.0f) { w3 |= 1u << (J); a3 = 0.0f; }            \
    } while (0)

#define STASH()                                                             \
    do {                                                                    \
        bits[(hloc * 4u + 0u) * 17u + wcl] = w0;                            \
        bits[(hloc * 4u + 1u) * 17u + wcl] = w1;                            \
        bits[(hloc * 4u + 2u) * 17u + wcl] = w2;                            \
        bits[(hloc * 4u + 3u) * 17u + wcl] = w3;                            \
        w0 = w1 = w2 = w3 = 0u;                                             \
    } while (0)

#define HOIST()                                                             \
    do {                                                                    \
        r0 = bits[(h0s + 0u) * 17u + wcs];                                  \
        r1 = bits[(h0s + 1u) * 17u + wcs];                                  \
        r2 = bits[(h0s + 2u) * 17u + wcs];                                  \
        r3 = bits[(h0s + 3u) * 17u + wcs];                                  \
    } while (0)

#define STORE(TP, J)                                                        \
    do {                                                                    \
        float4 v;                                                           \
        v.x = (float)((r0 >> (J)) & 1u);                                    \
        v.y = (float)((r1 >> (J)) & 1u);                                    \
        v.z = (float)((r2 >> (J)) & 1u);                                    \
        v.w = (float)((r3 >> (J)) & 1u);                                    \
        o4[((size_t)(rbase + (TP)) << 13) + cidx] = v;                      \
    } while (0)

    // ---- G0: scan planes 0..31 (read-only prologue) ----
#pragma unroll
    for (int j = 0; j < 32; ++j) SCAN(j, j);
    STASH();
    __syncthreads();
    HOIST();

    // ---- G1: scan 32..63 interleaved with store 0..31 ----
#pragma unroll
    for (int j = 0; j < 32; ++j) { SCAN(32 + j, j); STORE(j, j); }
    __syncthreads();                          // all waves past HOIST/loop
    STASH();
    __syncthreads();
    HOIST();

    // ---- G2: scan 64..95 interleaved with store 32..63 ----
#pragma unroll
    for (int j = 0; j < 32; ++j) { SCAN(64 + j, j); STORE(32 + j, j); }
    __syncthreads();
    STASH();
    __syncthreads();
    HOIST();

    // ---- G3 (tail): scan 96..99 interleaved with first stores of 64..95 ----
#pragma unroll
    for (int j = 0; j < 4; ++j)  { SCAN(96 + j, j); STORE(64 + j, j); }
#pragma unroll
    for (int j = 4; j < 32; ++j) STORE(64 + j, j);
    __syncthreads();
    STASH();                                  // words hold bits 0..3
    __syncthreads();
    HOIST();
#pragma unroll
    for (int j = 0; j < 4; ++j) STORE(96 + j, j);

#undef SCAN
#undef STASH
#undef HOIST
#undef STORE
}

extern "C" void kernel_launch(void* const* d_in, const int* in_sizes, int n_in,
                              void* d_out, int out_size, void* d_ws, size_t ws_size,
                              hipStream_t stream) {
    (void)in_sizes; (void)n_in; (void)out_size; (void)d_ws; (void)ws_size;
    const float* x = (const float*)d_in[0];
    float* out = (float*)d_out;
    hipLaunchKernelGGL(spike_pipe, dim3(256), dim3(256), 0, stream, x, out);
}